// Round 5
// baseline (68.523 us; speedup 1.0000x reference)
//
#include <hip/hip_runtime.h>
#include <hip/hip_bf16.h>
#include <stdint.h>

// RefBasedDeepMetric: out[b] = ||x_b@W + b||^2 + mean_r||refs_r@W + b||^2 - 2*(x_b@W + b).t
// where t = (mean_r refs_r)@W + b.  Both big terms are row-norm-reduced 4096x1024x1024
// GEMMs -> fused bf16 MFMA kernel, no MxN output materialization.
// R1: removed hipMemsetAsync (was 40us slow byte-fill); atomic-free colsum; fused prep.
// R2: fix zeroing — refrow was never cleared (accumulated across graph replays).
// R3: k_main double-buffered prefetch (T3 minimum 2-phase); prep rebalance (refs 512 blocks).
// R5: depth-2 counted-vmcnt pipeline (T3/T4: vmcnt(8), never full drain in steady state),
//     setprio around MFMA clusters (T5), t-vector computed in k_main prologue (k_tvec dropped).

typedef __attribute__((ext_vector_type(8))) short short8;
typedef __attribute__((ext_vector_type(4))) float f32x4;

__device__ __forceinline__ short f2bf(float f) {
  uint32_t u = __builtin_bit_cast(uint32_t, f);
  uint32_t r = (u + 0x7fffu + ((u >> 16) & 1u)) >> 16;  // RNE
  return (short)r;
}
__device__ __forceinline__ float bf2f(short s) {
  uint32_t u = ((uint32_t)(uint16_t)s) << 16;
  return __builtin_bit_cast(float, u);
}

// ---- workspace layout (bytes) ----
#define WS_XB 0u           // x bf16            4096*1024*2 = 8388608
#define WS_RB 8388608u     // refs bf16         8388608
#define WS_WT 16777216u    // W^T bf16          2097152
#define WS_CP 18874368u    // colsum partials   512*1024*4 = 2097152
#define WS_CS 20971520u    // colsum f32        4096
#define WS_XP 20979712u    // xpart f32         16384
#define WS_RR 20996096u    // refrow f32        16384

// ---- fused prep: convert x, convert refs (+colsum partials), transpose W, zero accs ----
// blocks [0,512): x f32->bf16             blocks [512,1024): refs f32->bf16 + colsum partials
// blocks [1024,1280): W transpose->bf16   blocks [1280,1284): zero xpart+refrow
__global__ __launch_bounds__(256) void k_prep(
    const float* __restrict__ x, const float* __restrict__ refs,
    const float* __restrict__ W, short* __restrict__ xb, short* __restrict__ rb,
    short* __restrict__ wt, float* __restrict__ cspart, float* __restrict__ zacc) {
  __shared__ short tile[64][68];
  const int b = blockIdx.x, t = threadIdx.x;
  if (b < 512) {
    // convert x: 1048576 float4s, grid-stride over 512*256 threads (8 iters)
    for (int i = b * 256 + t; i < 1048576; i += 512 * 256) {
      float4 v = ((const float4*)x)[i];
      uint32_t lo = (uint16_t)f2bf(v.x) | ((uint32_t)(uint16_t)f2bf(v.y) << 16);
      uint32_t hi = (uint16_t)f2bf(v.z) | ((uint32_t)(uint16_t)f2bf(v.w) << 16);
      ((uint2*)xb)[i] = make_uint2(lo, hi);
    }
  } else if (b < 1024) {
    // refs: 8 rows per block, thread owns 4 columns; partial colsums, no atomics
    const int rblk = b - 512;
    const int c0 = t * 4;
    float s0 = 0.f, s1 = 0.f, s2 = 0.f, s3 = 0.f;
    for (int r = rblk * 8; r < rblk * 8 + 8; ++r) {
      float4 v = *(const float4*)&refs[(size_t)r * 1024 + c0];
      s0 += v.x; s1 += v.y; s2 += v.z; s3 += v.w;
      uint32_t lo = (uint16_t)f2bf(v.x) | ((uint32_t)(uint16_t)f2bf(v.y) << 16);
      uint32_t hi = (uint16_t)f2bf(v.z) | ((uint32_t)(uint16_t)f2bf(v.w) << 16);
      *(uint2*)&rb[(size_t)r * 1024 + c0] = make_uint2(lo, hi);
    }
    cspart[rblk * 1024 + c0 + 0] = s0;
    cspart[rblk * 1024 + c0 + 1] = s1;
    cspart[rblk * 1024 + c0 + 2] = s2;
    cspart[rblk * 1024 + c0 + 3] = s3;
  } else if (b < 1280) {
    // transpose-convert W [k][n] f32 -> Wt [n][k] bf16, 64x64 tiles
    const int tb = b - 1024;
    const int tk = (tb >> 4) * 64, tn = (tb & 15) * 64;
    const int kk = t >> 4, nn4 = (t & 15) * 4;
#pragma unroll
    for (int p = 0; p < 4; ++p) {
      int k = kk + p * 16;
      float4 v = *(const float4*)&W[(size_t)(tk + k) * 1024 + tn + nn4];
      tile[nn4 + 0][k] = f2bf(v.x);
      tile[nn4 + 1][k] = f2bf(v.y);
      tile[nn4 + 2][k] = f2bf(v.z);
      tile[nn4 + 3][k] = f2bf(v.w);
    }
    __syncthreads();
    const int nn = t >> 4, kk4 = (t & 15) * 4;
#pragma unroll
    for (int p = 0; p < 4; ++p) {
      int n = nn + p * 16;
      uint32_t lo = (uint16_t)tile[n][kk4 + 0] | ((uint32_t)(uint16_t)tile[n][kk4 + 1] << 16);
      uint32_t hi = (uint16_t)tile[n][kk4 + 2] | ((uint32_t)(uint16_t)tile[n][kk4 + 3] << 16);
      *(uint2*)&wt[(size_t)(tn + n) * 1024 + tk + kk4] = make_uint2(lo, hi);
    }
  } else {
    // zero xpart + refrow: 8192 floats = 2048 float4s; 1024 threads x 2 each
    const int i = (b - 1280) * 256 + t;
    ((float4*)zacc)[i]        = make_float4(0.f, 0.f, 0.f, 0.f);
    ((float4*)zacc)[i + 1024] = make_float4(0.f, 0.f, 0.f, 0.f);
  }
}

// ---- colsum[k] = sum_p cspart[p][k]; 32 blocks x 32 cols, 8 partial-groups/LDS-reduce ----
__global__ void k_colsum(const float* __restrict__ cspart, float* __restrict__ colsum) {
  __shared__ float sh[8][32];
  const int t = threadIdx.x;
  const int c = t & 31, pg = t >> 5;
  const int k = blockIdx.x * 32 + c;
  float s = 0.f;
  for (int i = 0; i < 64; ++i) s += cspart[(size_t)(pg * 64 + i) * 1024 + k];
  sh[pg][c] = s;
  __syncthreads();
  if (t < 32) {
    float tot = 0.f;
#pragma unroll
    for (int g = 0; g < 8; ++g) tot += sh[g][t];
    colsum[blockIdx.x * 32 + t] = tot;
  }
}

// ---- main fused GEMM: per-row sum(v^2) and sum(v*t), v = row@W + b ----
// 128x128 tile, BK=64, 4 waves (2x2), 16x16x32 bf16 MFMA.
// Depth-2 prefetch, counted vmcnt(8) (T3/T4), setprio on MFMA (T5).
// t-panel computed per block in prologue (overlaps first two tiles' load latency).
__global__ __launch_bounds__(256) void k_main(
    const short* __restrict__ Xb, const short* __restrict__ Rb,
    const short* __restrict__ Wt, const float* __restrict__ bias,
    const float* __restrict__ colsum, float* __restrict__ xpart,
    float* __restrict__ refrow) {
  __shared__ __align__(16) short As[2][128 * 64];
  __shared__ __align__(16) short Bs[2][128 * 64];
  __shared__ float tlds[128], blds[128];
  __shared__ float tpart[128][2];
  const int t = threadIdx.x;
  const int w = t >> 6, l = t & 63;
  const int wr = w >> 1, wc = w & 1;
  const int bx = blockIdx.x;
  const int nt = bx & 7;        // round-robin dispatch: all blocks with nt=i land on XCD i -> Wt panel L2-resident
  const int mt = bx >> 3;       // 0..63 ; <32 -> x rows, >=32 -> refs rows
  const bool is_x = (mt < 32);
  const short* Am = is_x ? Xb : Rb;
  const int m0 = (is_x ? mt : (mt - 32)) * 128;
  const int n0 = nt * 128;

  const int srow = t >> 3;   // 0..31
  const int sslot = t & 7;   // 16B slot within 128B row

  f32x4 acc[4][4] = {};

  auto stage = [&](int buf, int kt) {
    const int k0 = kt * 64;
#pragma unroll
    for (int issue = 0; issue < 4; ++issue) {
      const int row = srow + issue * 32;
      const int sg = sslot ^ (row & 7);  // pre-swizzled global source (rule #21)
      const short* ga = Am + ((size_t)(m0 + row) * 1024 + k0 + sg * 8);
      const short* gb = Wt + ((size_t)(n0 + row) * 1024 + k0 + sg * 8);
      char* la = (char*)&As[buf][0] + issue * 4096 + w * 1024;
      char* lb = (char*)&Bs[buf][0] + issue * 4096 + w * 1024;
      __builtin_amdgcn_global_load_lds(
          (const __attribute__((address_space(1))) unsigned int*)ga,
          (__attribute__((address_space(3))) unsigned int*)la, 16, 0, 0);
      __builtin_amdgcn_global_load_lds(
          (const __attribute__((address_space(1))) unsigned int*)gb,
          (__attribute__((address_space(3))) unsigned int*)lb, 16, 0, 0);
    }
  };

  // prologue: issue first two tiles, then compute t-panel while they fly
  stage(0, 0);
  stage(1, 1);
  {
    const int n_off = t & 127, half = t >> 7;
    const short* wrow = Wt + (size_t)(n0 + n_off) * 1024 + half * 512;
    const float* cs = colsum + half * 512;
    float s = 0.f;
    for (int i = 0; i < 64; ++i) {
      short8 wv = *(const short8*)(wrow + i * 8);
      float4 c0 = *(const float4*)(cs + i * 8);
      float4 c1 = *(const float4*)(cs + i * 8 + 4);
      s += c0.x * bf2f(wv[0]) + c0.y * bf2f(wv[1]) + c0.z * bf2f(wv[2]) + c0.w * bf2f(wv[3])
         + c1.x * bf2f(wv[4]) + c1.y * bf2f(wv[5]) + c1.z * bf2f(wv[6]) + c1.w * bf2f(wv[7]);
    }
    tpart[n_off][half] = s * (1.0f / 4096.0f);
  }
  __syncthreads();
  if (t < 128) {
    const float bv = bias[n0 + t];
    blds[t] = bv;
    tlds[t] = tpart[t][0] + tpart[t][1] + bv;
  }

  // K-loop: depth-2 pipeline. At iter kt: tiles kt (landing) and kt+1 in flight.
  // Wait only for tile kt's 8 loads (vmcnt(8)); stage kt+2 after both barriers.
  for (int kt = 0; kt < 16; ++kt) {
    if (kt < 15) asm volatile("s_waitcnt vmcnt(8)" ::: "memory");
    else         asm volatile("s_waitcnt vmcnt(0)" ::: "memory");
    __builtin_amdgcn_s_barrier();   // tile kt's LDS writes visible to all waves
    const int cur = kt & 1;
#pragma unroll
    for (int kk = 0; kk < 2; ++kk) {
      short8 af[4], bfr[4];
#pragma unroll
      for (int i = 0; i < 4; ++i) {
        const int ra = wr * 64 + i * 16 + (l & 15);
        const int rbw = wc * 64 + i * 16 + (l & 15);
        const int s = (l >> 4) + kk * 4;
        af[i]  = *(const short8*)&As[cur][ra * 64 + ((s ^ (ra & 7)) * 8)];
        bfr[i] = *(const short8*)&Bs[cur][rbw * 64 + ((s ^ (rbw & 7)) * 8)];
      }
      __builtin_amdgcn_s_setprio(1);
#pragma unroll
      for (int i = 0; i < 4; ++i)
#pragma unroll
        for (int j2 = 0; j2 < 4; ++j2)
          acc[i][j2] = __builtin_amdgcn_mfma_f32_16x16x32_bf16(af[i], bfr[j2], acc[i][j2], 0, 0, 0);
      __builtin_amdgcn_s_setprio(0);
    }
    __builtin_amdgcn_s_barrier();   // all waves done reading buf[cur]
    if (kt + 2 < 16) stage(cur, kt + 2);
  }

  // epilogue: v = acc + bias[col]; per-row sums of v^2 and v*t[col]
  float bv[4], tvv[4];
#pragma unroll
  for (int n4 = 0; n4 < 4; ++n4) {
    const int ci = wc * 64 + n4 * 16 + (l & 15);
    bv[n4] = blds[ci];
    tvv[n4] = tlds[ci];
  }
#pragma unroll
  for (int m4 = 0; m4 < 4; ++m4) {
#pragma unroll
    for (int j = 0; j < 4; ++j) {
      float sq = 0.f, cr = 0.f;
#pragma unroll
      for (int n4 = 0; n4 < 4; ++n4) {
        const float v = acc[m4][n4][j] + bv[n4];
        sq += v * v;
        cr += v * tvv[n4];
      }
#pragma unroll
      for (int off = 1; off < 16; off <<= 1) {
        sq += __shfl_xor(sq, off, 64);
        cr += __shfl_xor(cr, off, 64);
      }
      if ((l & 15) == 0) {
        const int rm = m0 + wr * 64 + m4 * 16 + (l >> 4) * 4 + j;
        if (is_x) atomicAdd(&xpart[rm], sq - 2.0f * cr);
        else      atomicAdd(&refrow[rm], sq);
      }
    }
  }
}

// ---- tail: scalar = mean(refrow); out[b] = xpart[b] + scalar ----
__global__ void k_tail(const float* __restrict__ refrow, const float* __restrict__ xpart,
                       float* __restrict__ out) {
  __shared__ float sh[16];
  const int t = threadIdx.x;  // 1024 threads = 16 waves
  float s = 0.f;
  for (int i = t; i < 4096; i += 1024) s += refrow[i];
#pragma unroll
  for (int off = 32; off; off >>= 1) s += __shfl_down(s, off, 64);
  const int w = t >> 6, l = t & 63;
  if (l == 0) sh[w] = s;
  __syncthreads();
  if (t == 0) {
    float tot = 0.f;
#pragma unroll
    for (int i = 0; i < 16; ++i) tot += sh[i];
    sh[0] = tot * (1.0f / 4096.0f);
  }
  __syncthreads();
  const float ms = sh[0];
  for (int i = t; i < 4096; i += 1024) out[i] = xpart[i] + ms;
}

extern "C" void kernel_launch(void* const* d_in, const int* in_sizes, int n_in,
                              void* d_out, int out_size, void* d_ws, size_t ws_size,
                              hipStream_t stream) {
  const float* x    = (const float*)d_in[0];
  const float* refs = (const float*)d_in[1];
  const float* W    = (const float*)d_in[2];
  const float* bias = (const float*)d_in[3];
  float* out = (float*)d_out;
  char* ws = (char*)d_ws;

  short* xb     = (short*)(ws + WS_XB);
  short* rb     = (short*)(ws + WS_RB);
  short* wt     = (short*)(ws + WS_WT);
  float* cspart = (float*)(ws + WS_CP);
  float* colsum = (float*)(ws + WS_CS);
  float* xpart  = (float*)(ws + WS_XP);
  float* refrow = (float*)(ws + WS_RR);

  hipLaunchKernelGGL(k_prep, dim3(1284), dim3(256), 0, stream, x, refs, W, xb, rb, wt, cspart, xpart);
  hipLaunchKernelGGL(k_colsum, dim3(32), dim3(256), 0, stream, cspart, colsum);
  hipLaunchKernelGGL(k_main, dim3(512), dim3(256), 0, stream, xb, rb, wt, bias, colsum, xpart, refrow);
  hipLaunchKernelGGL(k_tail, dim3(1), dim3(1024), 0, stream, refrow, xpart, out);
}

// Round 6
// 55.264 us; speedup vs baseline: 1.2399x; 1.2399x over previous
//
#include <hip/hip_runtime.h>
#include <hip/hip_bf16.h>
#include <stdint.h>

// RefBasedDeepMetric: out[b] = ||x_b@W + b||^2 + mean_r||refs_r@W + b||^2 - 2*(x_b@W + b).t
// where t = (mean_r refs_r)@W + b.  Both big terms are row-norm-reduced 4096x1024x1024
// GEMMs -> fused bf16 MFMA kernel, no MxN output materialization.
// R1: removed hipMemsetAsync (was 40us slow byte-fill); atomic-free colsum; fused prep.
// R2: fix zeroing — refrow was never cleared (accumulated across graph replays).
// R3: k_main double-buffered prefetch; prep rebalance (refs 512 blocks).
// R5: depth-2 counted-vmcnt pipeline + setprio; t-panel prologue (REGRESSED: 64x redundant,
//     +50MB scattered FETCH, MfmaUtil 12.5%).
// R6: revert prologue (k_tvec restored, epilogue reads tv/bias direct); k_main 512 threads
//     / 8 waves (wave tile 64x32) -> 16 waves/CU for latency hiding; vmcnt(4) depth-2.

typedef __attribute__((ext_vector_type(8))) short short8;
typedef __attribute__((ext_vector_type(4))) float f32x4;

__device__ __forceinline__ short f2bf(float f) {
  uint32_t u = __builtin_bit_cast(uint32_t, f);
  uint32_t r = (u + 0x7fffu + ((u >> 16) & 1u)) >> 16;  // RNE
  return (short)r;
}
__device__ __forceinline__ float bf2f(short s) {
  uint32_t u = ((uint32_t)(uint16_t)s) << 16;
  return __builtin_bit_cast(float, u);
}

// ---- workspace layout (bytes) ----
#define WS_XB 0u           // x bf16            4096*1024*2 = 8388608
#define WS_RB 8388608u     // refs bf16         8388608
#define WS_WT 16777216u    // W^T bf16          2097152
#define WS_CP 18874368u    // colsum partials   512*1024*4 = 2097152
#define WS_CS 20971520u    // colsum f32        4096
#define WS_TV 20975616u    // t vector f32      4096
#define WS_XP 20979712u    // xpart f32         16384
#define WS_RR 20996096u    // refrow f32        16384

// ---- fused prep: convert x, convert refs (+colsum partials), transpose W, zero accs ----
__global__ __launch_bounds__(256) void k_prep(
    const float* __restrict__ x, const float* __restrict__ refs,
    const float* __restrict__ W, short* __restrict__ xb, short* __restrict__ rb,
    short* __restrict__ wt, float* __restrict__ cspart, float* __restrict__ zacc) {
  __shared__ short tile[64][68];
  const int b = blockIdx.x, t = threadIdx.x;
  if (b < 512) {
    for (int i = b * 256 + t; i < 1048576; i += 512 * 256) {
      float4 v = ((const float4*)x)[i];
      uint32_t lo = (uint16_t)f2bf(v.x) | ((uint32_t)(uint16_t)f2bf(v.y) << 16);
      uint32_t hi = (uint16_t)f2bf(v.z) | ((uint32_t)(uint16_t)f2bf(v.w) << 16);
      ((uint2*)xb)[i] = make_uint2(lo, hi);
    }
  } else if (b < 1024) {
    const int rblk = b - 512;
    const int c0 = t * 4;
    float s0 = 0.f, s1 = 0.f, s2 = 0.f, s3 = 0.f;
    for (int r = rblk * 8; r < rblk * 8 + 8; ++r) {
      float4 v = *(const float4*)&refs[(size_t)r * 1024 + c0];
      s0 += v.x; s1 += v.y; s2 += v.z; s3 += v.w;
      uint32_t lo = (uint16_t)f2bf(v.x) | ((uint32_t)(uint16_t)f2bf(v.y) << 16);
      uint32_t hi = (uint16_t)f2bf(v.z) | ((uint32_t)(uint16_t)f2bf(v.w) << 16);
      *(uint2*)&rb[(size_t)r * 1024 + c0] = make_uint2(lo, hi);
    }
    cspart[rblk * 1024 + c0 + 0] = s0;
    cspart[rblk * 1024 + c0 + 1] = s1;
    cspart[rblk * 1024 + c0 + 2] = s2;
    cspart[rblk * 1024 + c0 + 3] = s3;
  } else if (b < 1280) {
    const int tb = b - 1024;
    const int tk = (tb >> 4) * 64, tn = (tb & 15) * 64;
    const int kk = t >> 4, nn4 = (t & 15) * 4;
#pragma unroll
    for (int p = 0; p < 4; ++p) {
      int k = kk + p * 16;
      float4 v = *(const float4*)&W[(size_t)(tk + k) * 1024 + tn + nn4];
      tile[nn4 + 0][k] = f2bf(v.x);
      tile[nn4 + 1][k] = f2bf(v.y);
      tile[nn4 + 2][k] = f2bf(v.z);
      tile[nn4 + 3][k] = f2bf(v.w);
    }
    __syncthreads();
    const int nn = t >> 4, kk4 = (t & 15) * 4;
#pragma unroll
    for (int p = 0; p < 4; ++p) {
      int n = nn + p * 16;
      uint32_t lo = (uint16_t)tile[n][kk4 + 0] | ((uint32_t)(uint16_t)tile[n][kk4 + 1] << 16);
      uint32_t hi = (uint16_t)tile[n][kk4 + 2] | ((uint32_t)(uint16_t)tile[n][kk4 + 3] << 16);
      *(uint2*)&wt[(size_t)(tn + n) * 1024 + tk + kk4] = make_uint2(lo, hi);
    }
  } else {
    const int i = (b - 1280) * 256 + t;
    ((float4*)zacc)[i]        = make_float4(0.f, 0.f, 0.f, 0.f);
    ((float4*)zacc)[i + 1024] = make_float4(0.f, 0.f, 0.f, 0.f);
  }
}

// ---- colsum[k] = sum_p cspart[p][k] ----
__global__ void k_colsum(const float* __restrict__ cspart, float* __restrict__ colsum) {
  __shared__ float sh[8][32];
  const int t = threadIdx.x;
  const int c = t & 31, pg = t >> 5;
  const int k = blockIdx.x * 32 + c;
  float s = 0.f;
  for (int i = 0; i < 64; ++i) s += cspart[(size_t)(pg * 64 + i) * 1024 + k];
  sh[pg][c] = s;
  __syncthreads();
  if (t < 32) {
    float tot = 0.f;
#pragma unroll
    for (int g = 0; g < 8; ++g) tot += sh[g][t];
    colsum[blockIdx.x * 32 + t] = tot;
  }
}

// ---- t[n] = (colsum/R) @ W[:,n] + b[n], via Wt rows; one wave per n ----
__global__ void k_tvec(const short* __restrict__ Wt, const float* __restrict__ colsum,
                       const float* __restrict__ bias, float* __restrict__ tv) {
  int w = threadIdx.x >> 6, l = threadIdx.x & 63;
  int n = blockIdx.x * 4 + w;
  float s = 0.f;
  for (int k = l; k < 1024; k += 64)
    s += colsum[k] * (1.0f / 4096.0f) * bf2f(Wt[(size_t)n * 1024 + k]);
#pragma unroll
  for (int off = 32; off; off >>= 1) s += __shfl_down(s, off, 64);
  if (l == 0) tv[n] = s + bias[n];
}

// ---- main fused GEMM: per-row sum(v^2) and sum(v*t), v = row@W + b ----
// 128x128 tile, BK=64, 512 threads = 8 waves (2 row-groups x 4 col-groups),
// wave tile 64x32. Depth-2 prefetch, counted vmcnt(4) (T3/T4), setprio (T5).
// LDS via global_load_lds width=16; XOR-swizzle via pre-swizzled global src (rule #21).
__global__ __launch_bounds__(512) void k_main(
    const short* __restrict__ Xb, const short* __restrict__ Rb,
    const short* __restrict__ Wt, const float* __restrict__ bias,
    const float* __restrict__ tv, float* __restrict__ xpart,
    float* __restrict__ refrow) {
  __shared__ __align__(16) short As[2][128 * 64];
  __shared__ __align__(16) short Bs[2][128 * 64];
  const int t = threadIdx.x;
  const int w = t >> 6, l = t & 63;
  const int wr = w >> 2, wc = w & 3;       // 2x4 wave grid; wave tile 64 rows x 32 cols
  const int bx = blockIdx.x;
  const int nt = bx & 7;
  const int mt = bx >> 3;                  // <32 -> x rows, >=32 -> refs rows
  const bool is_x = (mt < 32);
  const short* Am = is_x ? Xb : Rb;
  const int m0 = (is_x ? mt : (mt - 32)) * 128;
  const int n0 = nt * 128;

  const int srow = t >> 3;   // 0..63
  const int sslot = t & 7;   // 16B slot within 128B row

  f32x4 acc[4][2] = {};

  auto stage = [&](int buf, int kt) {
    const int k0 = kt * 64;
#pragma unroll
    for (int issue = 0; issue < 2; ++issue) {
      const int row = srow + issue * 64;
      const int sg = sslot ^ (row & 7);  // pre-swizzled global source
      const short* ga = Am + ((size_t)(m0 + row) * 1024 + k0 + sg * 8);
      const short* gb = Wt + ((size_t)(n0 + row) * 1024 + k0 + sg * 8);
      char* la = (char*)&As[buf][0] + issue * 8192 + w * 1024;  // + lane*16 implicit
      char* lb = (char*)&Bs[buf][0] + issue * 8192 + w * 1024;
      __builtin_amdgcn_global_load_lds(
          (const __attribute__((address_space(1))) unsigned int*)ga,
          (__attribute__((address_space(3))) unsigned int*)la, 16, 0, 0);
      __builtin_amdgcn_global_load_lds(
          (const __attribute__((address_space(1))) unsigned int*)gb,
          (__attribute__((address_space(3))) unsigned int*)lb, 16, 0, 0);
    }
  };

  // prologue: stage tiles 0 and 1 (4 loads per wave per tile)
  stage(0, 0);
  stage(1, 1);

  // K-loop: depth-2 pipeline. At iter kt: tile kt landing, kt+1 in flight.
  for (int kt = 0; kt < 16; ++kt) {
    if (kt < 15) asm volatile("s_waitcnt vmcnt(4)" ::: "memory");
    else         asm volatile("s_waitcnt vmcnt(0)" ::: "memory");
    __builtin_amdgcn_s_barrier();   // tile kt's LDS writes visible
    const int cur = kt & 1;
#pragma unroll
    for (int kk = 0; kk < 2; ++kk) {
      short8 af[4], bfr[2];
#pragma unroll
      for (int i = 0; i < 4; ++i) {
        const int ra = wr * 64 + i * 16 + (l & 15);
        const int s = (l >> 4) + kk * 4;
        af[i] = *(const short8*)&As[cur][ra * 64 + ((s ^ (ra & 7)) * 8)];
      }
#pragma unroll
      for (int j = 0; j < 2; ++j) {
        const int rbw = wc * 32 + j * 16 + (l & 15);
        const int s = (l >> 4) + kk * 4;
        bfr[j] = *(const short8*)&Bs[cur][rbw * 64 + ((s ^ (rbw & 7)) * 8)];
      }
      __builtin_amdgcn_s_setprio(1);
#pragma unroll
      for (int i = 0; i < 4; ++i)
#pragma unroll
        for (int j = 0; j < 2; ++j)
          acc[i][j] = __builtin_amdgcn_mfma_f32_16x16x32_bf16(af[i], bfr[j], acc[i][j], 0, 0, 0);
      __builtin_amdgcn_s_setprio(0);
    }
    __builtin_amdgcn_s_barrier();   // all waves done reading buf[cur]
    if (kt + 2 < 16) stage(cur, kt + 2);
  }

  // epilogue: v = acc + bias[col]; per-row sums of v^2 and v*t[col]
  float bv[2], tvv[2];
#pragma unroll
  for (int n2 = 0; n2 < 2; ++n2) {
    const int col = n0 + wc * 32 + n2 * 16 + (l & 15);
    bv[n2] = bias[col];
    tvv[n2] = tv[col];
  }
#pragma unroll
  for (int m4 = 0; m4 < 4; ++m4) {
#pragma unroll
    for (int j = 0; j < 4; ++j) {
      float sq = 0.f, cr = 0.f;
#pragma unroll
      for (int n2 = 0; n2 < 2; ++n2) {
        const float v = acc[m4][n2][j] + bv[n2];
        sq += v * v;
        cr += v * tvv[n2];
      }
#pragma unroll
      for (int off = 1; off < 16; off <<= 1) {
        sq += __shfl_xor(sq, off, 64);
        cr += __shfl_xor(cr, off, 64);
      }
      if ((l & 15) == 0) {
        const int rm = m0 + wr * 64 + m4 * 16 + (l >> 4) * 4 + j;
        if (is_x) atomicAdd(&xpart[rm], sq - 2.0f * cr);
        else      atomicAdd(&refrow[rm], sq);
      }
    }
  }
}

// ---- tail: scalar = mean(refrow); out[b] = xpart[b] + scalar ----
__global__ void k_tail(const float* __restrict__ refrow, const float* __restrict__ xpart,
                       float* __restrict__ out) {
  __shared__ float sh[16];
  const int t = threadIdx.x;  // 1024 threads = 16 waves
  float s = 0.f;
  for (int i = t; i < 4096; i += 1024) s += refrow[i];
#pragma unroll
  for (int off = 32; off; off >>= 1) s += __shfl_down(s, off, 64);
  const int w = t >> 6, l = t & 63;
  if (l == 0) sh[w] = s;
  __syncthreads();
  if (t == 0) {
    float tot = 0.f;
#pragma unroll
    for (int i = 0; i < 16; ++i) tot += sh[i];
    sh[0] = tot * (1.0f / 4096.0f);
  }
  __syncthreads();
  const float ms = sh[0];
  for (int i = t; i < 4096; i += 1024) out[i] = xpart[i] + ms;
}

extern "C" void kernel_launch(void* const* d_in, const int* in_sizes, int n_in,
                              void* d_out, int out_size, void* d_ws, size_t ws_size,
                              hipStream_t stream) {
  const float* x    = (const float*)d_in[0];
  const float* refs = (const float*)d_in[1];
  const float* W    = (const float*)d_in[2];
  const float* bias = (const float*)d_in[3];
  float* out = (float*)d_out;
  char* ws = (char*)d_ws;

  short* xb     = (short*)(ws + WS_XB);
  short* rb     = (short*)(ws + WS_RB);
  short* wt     = (short*)(ws + WS_WT);
  float* cspart = (float*)(ws + WS_CP);
  float* colsum = (float*)(ws + WS_CS);
  float* tvv    = (float*)(ws + WS_TV);
  float* xpart  = (float*)(ws + WS_XP);
  float* refrow = (float*)(ws + WS_RR);

  hipLaunchKernelGGL(k_prep, dim3(1284), dim3(256), 0, stream, x, refs, W, xb, rb, wt, cspart, xpart);
  hipLaunchKernelGGL(k_colsum, dim3(32), dim3(256), 0, stream, cspart, colsum);
  hipLaunchKernelGGL(k_tvec, dim3(256), dim3(256), 0, stream, wt, colsum, bias, tvv);
  hipLaunchKernelGGL(k_main, dim3(512), dim3(512), 0, stream, xb, rb, wt, bias, tvv, xpart, refrow);
  hipLaunchKernelGGL(k_tail, dim3(1), dim3(1024), 0, stream, refrow, xpart, out);
}

// Round 7
// 51.441 us; speedup vs baseline: 1.3321x; 1.0743x over previous
//
#include <hip/hip_runtime.h>
#include <hip/hip_bf16.h>
#include <stdint.h>

// RefBasedDeepMetric: out[b] = ||x_b@W + b||^2 + mean_r||refs_r@W + b||^2 - 2*(x_b@W + b).t
// where t = (mean_r refs_r)@W + b.  Both big terms are row-norm-reduced 4096x1024x1024
// GEMMs -> fused bf16 MFMA kernel, no MxN output materialization.
// R1: removed hipMemsetAsync (was 40us slow byte-fill); atomic-free colsum; fused prep.
// R2: fix zeroing — refrow was never cleared (accumulated across graph replays).
// R3: k_main double-buffered prefetch; prep rebalance (refs 512 blocks).
// R5: t-panel prologue (REGRESSED: 64x redundant reads). R6: reverted; 8-wave k_main,
//     counted vmcnt depth-2 — neutral vs R4 => not wave-latency-bound.
// R7: XCD-aware mapping swap (mt=bx&63, nt=bx>>6): blocks sharing an A-panel now land on
//     the SAME XCD (bx%8 equal) -> A re-reads hit L2 instead of streaming ~134MB from L3.

typedef __attribute__((ext_vector_type(8))) short short8;
typedef __attribute__((ext_vector_type(4))) float f32x4;

__device__ __forceinline__ short f2bf(float f) {
  uint32_t u = __builtin_bit_cast(uint32_t, f);
  uint32_t r = (u + 0x7fffu + ((u >> 16) & 1u)) >> 16;  // RNE
  return (short)r;
}
__device__ __forceinline__ float bf2f(short s) {
  uint32_t u = ((uint32_t)(uint16_t)s) << 16;
  return __builtin_bit_cast(float, u);
}

// ---- workspace layout (bytes) ----
#define WS_XB 0u           // x bf16            4096*1024*2 = 8388608
#define WS_RB 8388608u     // refs bf16         8388608
#define WS_WT 16777216u    // W^T bf16          2097152
#define WS_CP 18874368u    // colsum partials   512*1024*4 = 2097152
#define WS_CS 20971520u    // colsum f32        4096
#define WS_TV 20975616u    // t vector f32      4096
#define WS_XP 20979712u    // xpart f32         16384
#define WS_RR 20996096u    // refrow f32        16384

// ---- fused prep: convert x, convert refs (+colsum partials), transpose W, zero accs ----
__global__ __launch_bounds__(256) void k_prep(
    const float* __restrict__ x, const float* __restrict__ refs,
    const float* __restrict__ W, short* __restrict__ xb, short* __restrict__ rb,
    short* __restrict__ wt, float* __restrict__ cspart, float* __restrict__ zacc) {
  __shared__ short tile[64][68];
  const int b = blockIdx.x, t = threadIdx.x;
  if (b < 512) {
    for (int i = b * 256 + t; i < 1048576; i += 512 * 256) {
      float4 v = ((const float4*)x)[i];
      uint32_t lo = (uint16_t)f2bf(v.x) | ((uint32_t)(uint16_t)f2bf(v.y) << 16);
      uint32_t hi = (uint16_t)f2bf(v.z) | ((uint32_t)(uint16_t)f2bf(v.w) << 16);
      ((uint2*)xb)[i] = make_uint2(lo, hi);
    }
  } else if (b < 1024) {
    const int rblk = b - 512;
    const int c0 = t * 4;
    float s0 = 0.f, s1 = 0.f, s2 = 0.f, s3 = 0.f;
    for (int r = rblk * 8; r < rblk * 8 + 8; ++r) {
      float4 v = *(const float4*)&refs[(size_t)r * 1024 + c0];
      s0 += v.x; s1 += v.y; s2 += v.z; s3 += v.w;
      uint32_t lo = (uint16_t)f2bf(v.x) | ((uint32_t)(uint16_t)f2bf(v.y) << 16);
      uint32_t hi = (uint16_t)f2bf(v.z) | ((uint32_t)(uint16_t)f2bf(v.w) << 16);
      *(uint2*)&rb[(size_t)r * 1024 + c0] = make_uint2(lo, hi);
    }
    cspart[rblk * 1024 + c0 + 0] = s0;
    cspart[rblk * 1024 + c0 + 1] = s1;
    cspart[rblk * 1024 + c0 + 2] = s2;
    cspart[rblk * 1024 + c0 + 3] = s3;
  } else if (b < 1280) {
    const int tb = b - 1024;
    const int tk = (tb >> 4) * 64, tn = (tb & 15) * 64;
    const int kk = t >> 4, nn4 = (t & 15) * 4;
#pragma unroll
    for (int p = 0; p < 4; ++p) {
      int k = kk + p * 16;
      float4 v = *(const float4*)&W[(size_t)(tk + k) * 1024 + tn + nn4];
      tile[nn4 + 0][k] = f2bf(v.x);
      tile[nn4 + 1][k] = f2bf(v.y);
      tile[nn4 + 2][k] = f2bf(v.z);
      tile[nn4 + 3][k] = f2bf(v.w);
    }
    __syncthreads();
    const int nn = t >> 4, kk4 = (t & 15) * 4;
#pragma unroll
    for (int p = 0; p < 4; ++p) {
      int n = nn + p * 16;
      uint32_t lo = (uint16_t)tile[n][kk4 + 0] | ((uint32_t)(uint16_t)tile[n][kk4 + 1] << 16);
      uint32_t hi = (uint16_t)tile[n][kk4 + 2] | ((uint32_t)(uint16_t)tile[n][kk4 + 3] << 16);
      *(uint2*)&wt[(size_t)(tn + n) * 1024 + tk + kk4] = make_uint2(lo, hi);
    }
  } else {
    const int i = (b - 1280) * 256 + t;
    ((float4*)zacc)[i]        = make_float4(0.f, 0.f, 0.f, 0.f);
    ((float4*)zacc)[i + 1024] = make_float4(0.f, 0.f, 0.f, 0.f);
  }
}

// ---- colsum[k] = sum_p cspart[p][k] ----
__global__ void k_colsum(const float* __restrict__ cspart, float* __restrict__ colsum) {
  __shared__ float sh[8][32];
  const int t = threadIdx.x;
  const int c = t & 31, pg = t >> 5;
  const int k = blockIdx.x * 32 + c;
  float s = 0.f;
  for (int i = 0; i < 64; ++i) s += cspart[(size_t)(pg * 64 + i) * 1024 + k];
  sh[pg][c] = s;
  __syncthreads();
  if (t < 32) {
    float tot = 0.f;
#pragma unroll
    for (int g = 0; g < 8; ++g) tot += sh[g][t];
    colsum[blockIdx.x * 32 + t] = tot;
  }
}

// ---- t[n] = (colsum/R) @ W[:,n] + b[n], via Wt rows; one wave per n ----
__global__ void k_tvec(const short* __restrict__ Wt, const float* __restrict__ colsum,
                       const float* __restrict__ bias, float* __restrict__ tv) {
  int w = threadIdx.x >> 6, l = threadIdx.x & 63;
  int n = blockIdx.x * 4 + w;
  float s = 0.f;
  for (int k = l; k < 1024; k += 64)
    s += colsum[k] * (1.0f / 4096.0f) * bf2f(Wt[(size_t)n * 1024 + k]);
#pragma unroll
  for (int off = 32; off; off >>= 1) s += __shfl_down(s, off, 64);
  if (l == 0) tv[n] = s + bias[n];
}

// ---- main fused GEMM: per-row sum(v^2) and sum(v*t), v = row@W + b ----
// 128x128 tile, BK=64, 512 threads = 8 waves (2 row-groups x 4 col-groups),
// wave tile 64x32. Depth-2 prefetch, counted vmcnt(4) (T3/T4), setprio (T5).
// R7 mapping: mt = bx&63, nt = bx>>6 -> same-A blocks co-located per XCD (L2 reuse).
__global__ __launch_bounds__(512) void k_main(
    const short* __restrict__ Xb, const short* __restrict__ Rb,
    const short* __restrict__ Wt, const float* __restrict__ bias,
    const float* __restrict__ tv, float* __restrict__ xpart,
    float* __restrict__ refrow) {
  __shared__ __align__(16) short As[2][128 * 64];
  __shared__ __align__(16) short Bs[2][128 * 64];
  const int t = threadIdx.x;
  const int w = t >> 6, l = t & 63;
  const int wr = w >> 2, wc = w & 3;       // 2x4 wave grid; wave tile 64 rows x 32 cols
  const int bx = blockIdx.x;
  const int nt = bx >> 6;                  // 0..7  (R7: was bx&7)
  const int mt = bx & 63;                  // 0..63 ; <32 -> x rows, >=32 -> refs rows
  const bool is_x = (mt < 32);
  const short* Am = is_x ? Xb : Rb;
  const int m0 = (is_x ? mt : (mt - 32)) * 128;
  const int n0 = nt * 128;

  const int srow = t >> 3;   // 0..63
  const int sslot = t & 7;   // 16B slot within 128B row

  f32x4 acc[4][2] = {};

  auto stage = [&](int buf, int kt) {
    const int k0 = kt * 64;
#pragma unroll
    for (int issue = 0; issue < 2; ++issue) {
      const int row = srow + issue * 64;
      const int sg = sslot ^ (row & 7);  // pre-swizzled global source (rule #21)
      const short* ga = Am + ((size_t)(m0 + row) * 1024 + k0 + sg * 8);
      const short* gb = Wt + ((size_t)(n0 + row) * 1024 + k0 + sg * 8);
      char* la = (char*)&As[buf][0] + issue * 8192 + w * 1024;
      char* lb = (char*)&Bs[buf][0] + issue * 8192 + w * 1024;
      __builtin_amdgcn_global_load_lds(
          (const __attribute__((address_space(1))) unsigned int*)ga,
          (__attribute__((address_space(3))) unsigned int*)la, 16, 0, 0);
      __builtin_amdgcn_global_load_lds(
          (const __attribute__((address_space(1))) unsigned int*)gb,
          (__attribute__((address_space(3))) unsigned int*)lb, 16, 0, 0);
    }
  };

  // prologue: stage tiles 0 and 1 (4 loads per wave per tile)
  stage(0, 0);
  stage(1, 1);

  // K-loop: depth-2 pipeline. At iter kt: tile kt landing, kt+1 in flight.
  for (int kt = 0; kt < 16; ++kt) {
    if (kt < 15) asm volatile("s_waitcnt vmcnt(4)" ::: "memory");
    else         asm volatile("s_waitcnt vmcnt(0)" ::: "memory");
    __builtin_amdgcn_s_barrier();   // tile kt's LDS writes visible
    const int cur = kt & 1;
#pragma unroll
    for (int kk = 0; kk < 2; ++kk) {
      short8 af[4], bfr[2];
#pragma unroll
      for (int i = 0; i < 4; ++i) {
        const int ra = wr * 64 + i * 16 + (l & 15);
        const int s = (l >> 4) + kk * 4;
        af[i] = *(const short8*)&As[cur][ra * 64 + ((s ^ (ra & 7)) * 8)];
      }
#pragma unroll
      for (int j = 0; j < 2; ++j) {
        const int rbw = wc * 32 + j * 16 + (l & 15);
        const int s = (l >> 4) + kk * 4;
        bfr[j] = *(const short8*)&Bs[cur][rbw * 64 + ((s ^ (rbw & 7)) * 8)];
      }
      __builtin_amdgcn_s_setprio(1);
#pragma unroll
      for (int i = 0; i < 4; ++i)
#pragma unroll
        for (int j = 0; j < 2; ++j)
          acc[i][j] = __builtin_amdgcn_mfma_f32_16x16x32_bf16(af[i], bfr[j], acc[i][j], 0, 0, 0);
      __builtin_amdgcn_s_setprio(0);
    }
    __builtin_amdgcn_s_barrier();   // all waves done reading buf[cur]
    if (kt + 2 < 16) stage(cur, kt + 2);
  }

  // epilogue: v = acc + bias[col]; per-row sums of v^2 and v*t[col]
  float bv[2], tvv[2];
#pragma unroll
  for (int n2 = 0; n2 < 2; ++n2) {
    const int col = n0 + wc * 32 + n2 * 16 + (l & 15);
    bv[n2] = bias[col];
    tvv[n2] = tv[col];
  }
#pragma unroll
  for (int m4 = 0; m4 < 4; ++m4) {
#pragma unroll
    for (int j = 0; j < 4; ++j) {
      float sq = 0.f, cr = 0.f;
#pragma unroll
      for (int n2 = 0; n2 < 2; ++n2) {
        const float v = acc[m4][n2][j] + bv[n2];
        sq += v * v;
        cr += v * tvv[n2];
      }
#pragma unroll
      for (int off = 1; off < 16; off <<= 1) {
        sq += __shfl_xor(sq, off, 64);
        cr += __shfl_xor(cr, off, 64);
      }
      if ((l & 15) == 0) {
        const int rm = m0 + wr * 64 + m4 * 16 + (l >> 4) * 4 + j;
        if (is_x) atomicAdd(&xpart[rm], sq - 2.0f * cr);
        else      atomicAdd(&refrow[rm], sq);
      }
    }
  }
}

// ---- tail: scalar = mean(refrow); out[b] = xpart[b] + scalar ----
__global__ void k_tail(const float* __restrict__ refrow, const float* __restrict__ xpart,
                       float* __restrict__ out) {
  __shared__ float sh[16];
  const int t = threadIdx.x;  // 1024 threads = 16 waves
  float s = 0.f;
  for (int i = t; i < 4096; i += 1024) s += refrow[i];
#pragma unroll
  for (int off = 32; off; off >>= 1) s += __shfl_down(s, off, 64);
  const int w = t >> 6, l = t & 63;
  if (l == 0) sh[w] = s;
  __syncthreads();
  if (t == 0) {
    float tot = 0.f;
#pragma unroll
    for (int i = 0; i < 16; ++i) tot += sh[i];
    sh[0] = tot * (1.0f / 4096.0f);
  }
  __syncthreads();
  const float ms = sh[0];
  for (int i = t; i < 4096; i += 1024) out[i] = xpart[i] + ms;
}

extern "C" void kernel_launch(void* const* d_in, const int* in_sizes, int n_in,
                              void* d_out, int out_size, void* d_ws, size_t ws_size,
                              hipStream_t stream) {
  const float* x    = (const float*)d_in[0];
  const float* refs = (const float*)d_in[1];
  const float* W    = (const float*)d_in[2];
  const float* bias = (const float*)d_in[3];
  float* out = (float*)d_out;
  char* ws = (char*)d_ws;

  short* xb     = (short*)(ws + WS_XB);
  short* rb     = (short*)(ws + WS_RB);
  short* wt     = (short*)(ws + WS_WT);
  float* cspart = (float*)(ws + WS_CP);
  float* colsum = (float*)(ws + WS_CS);
  float* tvv    = (float*)(ws + WS_TV);
  float* xpart  = (float*)(ws + WS_XP);
  float* refrow = (float*)(ws + WS_RR);

  hipLaunchKernelGGL(k_prep, dim3(1284), dim3(256), 0, stream, x, refs, W, xb, rb, wt, cspart, xpart);
  hipLaunchKernelGGL(k_colsum, dim3(32), dim3(256), 0, stream, cspart, colsum);
  hipLaunchKernelGGL(k_tvec, dim3(256), dim3(256), 0, stream, wt, colsum, bias, tvv);
  hipLaunchKernelGGL(k_main, dim3(512), dim3(512), 0, stream, xb, rb, wt, bias, tvv, xpart, refrow);
  hipLaunchKernelGGL(k_tail, dim3(1), dim3(1024), 0, stream, refrow, xpart, out);
}